// Round 7
// baseline (174.101 us; speedup 1.0000x reference)
//
#include <hip/hip_runtime.h>
#include <hip/hip_bf16.h>

// Problem constants
#define B_    4
#define T_    4096
#define C_    512
#define H_    8
#define D_    64
#define KS_   9
#define PAD_  4
#define MTOT  (B_ * T_)          // 16384
#define PLANE (MTOT * C_)        // elements per q/k/v plane
#define XU    (MTOT * C_ / 8)    // x units of 8 elements
#define WU    (C_ * C_ / 8)      // weight units of 8 elements

typedef __bf16 bf16_t;
typedef __bf16 bf16x8 __attribute__((ext_vector_type(8)));
typedef float  f32x4  __attribute__((ext_vector_type(4)));

// ---------------------------------------------------------------------------
// Fused fp32 -> bf16: x (XU units) then Wq,Wk,Wv,Wo (WU each), contiguous dst.
// ---------------------------------------------------------------------------
__global__ __launch_bounds__(256)
void conv_all(const float* __restrict__ x,  const float* __restrict__ Wq,
              const float* __restrict__ Wk, const float* __restrict__ Wv,
              const float* __restrict__ Wo, bf16_t* __restrict__ dst) {
  int i = blockIdx.x * 256 + threadIdx.x;
  const float* s;
  if (i < XU) {
    s = x + (size_t)i * 8;
  } else {
    int r = i - XU;
    int w = r >> 15;                       // WU = 1<<15
    const float* W = (w == 0) ? Wq : (w == 1) ? Wk : (w == 2) ? Wv : Wo;
    s = W + (size_t)(r & (WU - 1)) * 8;
  }
  float4 f0 = ((const float4*)s)[0];
  float4 f1 = ((const float4*)s)[1];
  bf16x8 o;
  o[0] = (bf16_t)f0.x; o[1] = (bf16_t)f0.y; o[2] = (bf16_t)f0.z; o[3] = (bf16_t)f0.w;
  o[4] = (bf16_t)f1.x; o[5] = (bf16_t)f1.y; o[6] = (bf16_t)f1.z; o[7] = (bf16_t)f1.w;
  ((bf16x8*)dst)[i] = o;
}

// ---------------------------------------------------------------------------
// GEMM main loop: C[M,N] = A[M,K]*W[N,K]^T. 128x128 tile, BK=64 (8 k-iters,
// 32 MFMA/wave per barrier), mfma_f32_16x16x32_bf16, global_load_lds w=16.
// XOR chunk swizzle: LDS[row][slot] holds global 16B-chunk (slot ^ (row&7)).
// At 128B row stride this spreads frag reads over all 32 banks.
// APLANE: A stored as per-head planes (b,h,t,d); BK=64 slab = one full head.
// ---------------------------------------------------------------------------
template <bool APLANE>
__device__ __forceinline__ void gemm_main(const bf16_t* __restrict__ A,
                                          const bf16_t* __restrict__ W,
                                          int m0, int n0, f32x4 acc[4][4]) {
  constexpr int K = C_;
  __shared__ __align__(16) bf16_t lsA[128 * 64];   // 16 KB
  __shared__ __align__(16) bf16_t lsB[128 * 64];   // 16 KB

  const int tid  = threadIdx.x;
  const int lane = tid & 63;
  const int wave = tid >> 6;
  const int wm   = (wave >> 1) * 64;
  const int wn   = (wave & 1) * 64;

  for (int k0 = 0; k0 < K; k0 += 64) {
    __syncthreads();   // previous iteration's LDS reads complete
#pragma unroll
    for (int s = 0; s < 4; ++s) {
      // unit u covers 16 B = 8 bf16: row = u>>3, slot = u&7.
      int u    = s * 256 + tid;
      int row  = u >> 3;
      int slot = u & 7;
      int c    = slot ^ (row & 7);           // swizzled global chunk
      const bf16_t* ga;
      if (APLANE) {
        int m = m0 + row;
        int b = m >> 12, t = m & (T_ - 1);
        int h = k0 >> 6;                     // BK=64 slab = exactly one head
        ga = A + (((size_t)(b * H_ + h) * T_ + t) * D_ + c * 8);
      } else {
        ga = A + ((size_t)(m0 + row) * K + k0 + c * 8);
      }
      const bf16_t* gb = W + ((size_t)(n0 + row) * K + k0 + c * 8);
      __builtin_amdgcn_global_load_lds(
          (const __attribute__((address_space(1))) unsigned int*)ga,
          (__attribute__((address_space(3))) unsigned int*)&lsA[u * 8], 16, 0, 0);
      __builtin_amdgcn_global_load_lds(
          (const __attribute__((address_space(1))) unsigned int*)gb,
          (__attribute__((address_space(3))) unsigned int*)&lsB[u * 8], 16, 0, 0);
    }
    __syncthreads();   // vmcnt drained before barrier -> staging visible

    const int rr = lane & 15;
    const int q  = lane >> 4;
#pragma unroll
    for (int kh = 0; kh < 2; ++kh) {
      const int cg = kh * 4 + q;             // global chunk wanted
      const int sl = (cg ^ (rr & 7)) << 3;   // swizzled LDS slot (elements)
      bf16x8 af[4], bfr[4];
#pragma unroll
      for (int i = 0; i < 4; ++i) {
        af[i]  = *(const bf16x8*)&lsA[(wm + i * 16 + rr) * 64 + sl];
        bfr[i] = *(const bf16x8*)&lsB[(wn + i * 16 + rr) * 64 + sl];
      }
#pragma unroll
      for (int i = 0; i < 4; ++i)
#pragma unroll
        for (int j = 0; j < 4; ++j)
          acc[i][j] = __builtin_amdgcn_mfma_f32_16x16x32_bf16(
              af[i], bfr[j], acc[i][j], 0, 0, 0);
    }
  }
}

// qkv GEMM: z in grid; writes bf16 per-head planes qkv[z][b][h][t][d].
__global__ __launch_bounds__(256, 2)
void qkv_gemm(const bf16_t* __restrict__ xb, const bf16_t* __restrict__ Wb,
              const float* __restrict__ bq, const float* __restrict__ bk,
              const float* __restrict__ bv, bf16_t* __restrict__ qkv) {
  const int z  = blockIdx.z;
  const int m0 = blockIdx.y * 128, n0 = blockIdx.x * 128;
  f32x4 acc[4][4] = {};
  gemm_main<false>(xb, Wb + (size_t)z * C_ * C_, m0, n0, acc);

  const float* bias = (z == 0) ? bq : (z == 1) ? bk : bv;
  const int tid = threadIdx.x, lane = tid & 63, wave = tid >> 6;
  const int wm = (wave >> 1) * 64, wn = (wave & 1) * 64;
  const int cn = lane & 15, rb = (lane >> 4) << 2;

  // C/D layout: col = lane&15, row = (lane>>4)*4 + reg  [m89]
  float bvals[4];
#pragma unroll
  for (int j = 0; j < 4; ++j) bvals[j] = bias[n0 + wn + j * 16 + cn];

  const int bb = m0 >> 12;              // batch (tile never crosses b)
  const int hh = (n0 + wn) >> 6;        // head (64-col aligned per wave)
  bf16_t* hb = qkv + (size_t)z * PLANE + (size_t)(bb * H_ + hh) * T_ * D_;
#pragma unroll
  for (int i = 0; i < 4; ++i) {
#pragma unroll
    for (int r = 0; r < 4; ++r) {
      int t = (m0 + wm + i * 16 + rb + r) & (T_ - 1);
      bf16_t* row = hb + (size_t)t * D_;
#pragma unroll
      for (int j = 0; j < 4; ++j)
        row[j * 16 + cn] = (bf16_t)(acc[i][j][r] + bvals[j]);
    }
  }
}

// Output GEMM: A = y in per-head planes; fp32 row-major [MTOT, C] out.
__global__ __launch_bounds__(256, 2)
void out_gemm(const bf16_t* __restrict__ y, const bf16_t* __restrict__ Wob,
              const float* __restrict__ bo, float* __restrict__ out) {
  const int m0 = blockIdx.y * 128, n0 = blockIdx.x * 128;
  f32x4 acc[4][4] = {};
  gemm_main<true>(y, Wob, m0, n0, acc);

  const int tid = threadIdx.x, lane = tid & 63, wave = tid >> 6;
  const int wm = (wave >> 1) * 64, wn = (wave & 1) * 64;
  const int cn = lane & 15, rb = (lane >> 4) << 2;
  float bvals[4];
#pragma unroll
  for (int j = 0; j < 4; ++j) bvals[j] = bo[n0 + wn + j * 16 + cn];
#pragma unroll
  for (int i = 0; i < 4; ++i) {
#pragma unroll
    for (int r = 0; r < 4; ++r) {
      int gm = m0 + wm + i * 16 + rb + r;
      float* orow = out + (size_t)gm * C_ + (n0 + wn);
#pragma unroll
      for (int j = 0; j < 4; ++j)
        orow[j * 16 + cn] = acc[i][j][r] + bvals[j];
    }
  }
}

// ---------------------------------------------------------------------------
// Neighborhood attention: 8 threads per (b,h,t), d-octet each; width-8
// shfl_xor score reduce; per-head plane I/O (fully coalesced).
// ---------------------------------------------------------------------------
__global__ __launch_bounds__(256)
void attn_kernel(const bf16_t* __restrict__ qkv, bf16_t* __restrict__ y) {
  const int tid  = threadIdx.x;
  const int sub  = tid & 7;
  const int tl   = tid >> 3;
  const int t    = blockIdx.x * 32 + tl;
  const int h    = blockIdx.y;
  const int b    = blockIdx.z;

  const size_t pl = (size_t)(b * H_ + h) * T_ * D_;
  const bf16_t* q = qkv + pl;
  const bf16_t* k = qkv + (size_t)PLANE + pl;
  const bf16_t* v = qkv + (size_t)2 * PLANE + pl;
  const int c = sub * 8;

  int tj[KS_];
#pragma unroll
  for (int j = 0; j < KS_; ++j) {
    int tt = t - PAD_ + j;
    tj[j] = tt < 0 ? 0 : (tt >= T_ ? T_ - 1 : tt);
  }

  bf16x8 q8 = *(const bf16x8*)(q + (size_t)t * D_ + c);
  float qf[8];
#pragma unroll
  for (int e = 0; e < 8; ++e) qf[e] = (float)q8[e];

  float s[KS_];
#pragma unroll
  for (int j = 0; j < KS_; ++j) {
    bf16x8 k8 = *(const bf16x8*)(k + (size_t)tj[j] * D_ + c);
    float d0 = 0.f;
#pragma unroll
    for (int e = 0; e < 8; ++e) d0 += qf[e] * (float)k8[e];
    s[j] = d0;
  }

#pragma unroll
  for (int m = 1; m < 8; m <<= 1)
#pragma unroll
    for (int j = 0; j < KS_; ++j) s[j] += __shfl_xor(s[j], m, 8);

  float mx = s[0];
#pragma unroll
  for (int j = 1; j < KS_; ++j) mx = fmaxf(mx, s[j]);
  float w[KS_], sum = 0.f;
#pragma unroll
  for (int j = 0; j < KS_; ++j) {
    w[j] = __expf((s[j] - mx) * 0.125f);   // scale = 1/sqrt(64)
    sum += w[j];
  }
  const float inv = 1.f / sum;
#pragma unroll
  for (int j = 0; j < KS_; ++j) w[j] *= inv;

  float o[8] = {0.f, 0.f, 0.f, 0.f, 0.f, 0.f, 0.f, 0.f};
#pragma unroll
  for (int j = 0; j < KS_; ++j) {
    bf16x8 v8 = *(const bf16x8*)(v + (size_t)tj[j] * D_ + c);
#pragma unroll
    for (int e = 0; e < 8; ++e) o[e] += w[j] * (float)v8[e];
  }
  bf16x8 o8;
#pragma unroll
  for (int e = 0; e < 8; ++e) o8[e] = (bf16_t)o[e];
  *(bf16x8*)(y + pl + (size_t)t * D_ + c) = o8;
}

// ---------------------------------------------------------------------------
extern "C" void kernel_launch(void* const* d_in, const int* in_sizes, int n_in,
                              void* d_out, int out_size, void* d_ws, size_t ws_size,
                              hipStream_t stream) {
  const float* x  = (const float*)d_in[0];
  const float* Wq = (const float*)d_in[1];
  const float* bq = (const float*)d_in[2];
  const float* Wk = (const float*)d_in[3];
  const float* bk = (const float*)d_in[4];
  const float* Wv = (const float*)d_in[5];
  const float* bv = (const float*)d_in[6];
  const float* Wo = (const float*)d_in[7];
  const float* bo = (const float*)d_in[8];
  float* out = (float*)d_out;

  // Workspace: xb 16MB | Wb 2MB | qkv 48MB | y 16MB  = 82 MB
  bf16_t* xb  = (bf16_t*)d_ws;
  bf16_t* Wb  = xb + (size_t)MTOT * C_;
  bf16_t* qkv = Wb + (size_t)4 * C_ * C_;
  bf16_t* y   = qkv + (size_t)3 * PLANE;

  conv_all<<<(XU + 4 * WU) / 256, 256, 0, stream>>>(x, Wq, Wk, Wv, Wo, xb);
  qkv_gemm<<<dim3(C_ / 128, MTOT / 128, 3), 256, 0, stream>>>(
      xb, Wb, bq, bk, bv, qkv);
  attn_kernel<<<dim3(T_ / 32, H_, B_), 256, 0, stream>>>(qkv, y);
  out_gemm<<<dim3(C_ / 128, MTOT / 128, 1), 256, 0, stream>>>(
      y, Wb + (size_t)3 * C_ * C_, bo, out);
}

// Round 8
// 171.279 us; speedup vs baseline: 1.0165x; 1.0165x over previous
//
#include <hip/hip_runtime.h>
#include <hip/hip_bf16.h>

// Problem constants
#define B_    4
#define T_    4096
#define C_    512
#define H_    8
#define D_    64
#define KS_   9
#define PAD_  4
#define MTOT  (B_ * T_)          // 16384
#define PLANE (MTOT * C_)        // elements per q/k/v plane
#define XU    (MTOT * C_ / 8)    // x units of 8 elements
#define WU    (C_ * C_ / 8)      // weight units of 8 elements

typedef __bf16 bf16_t;
typedef __bf16 bf16x8 __attribute__((ext_vector_type(8)));
typedef float  f32x4  __attribute__((ext_vector_type(4)));

// ---------------------------------------------------------------------------
// Fused fp32 -> bf16: x (XU units) then Wq,Wk,Wv,Wo (WU each), contiguous dst.
// ---------------------------------------------------------------------------
__global__ __launch_bounds__(256)
void conv_all(const float* __restrict__ x,  const float* __restrict__ Wq,
              const float* __restrict__ Wk, const float* __restrict__ Wv,
              const float* __restrict__ Wo, bf16_t* __restrict__ dst) {
  int i = blockIdx.x * 256 + threadIdx.x;
  const float* s;
  if (i < XU) {
    s = x + (size_t)i * 8;
  } else {
    int r = i - XU;
    int w = r >> 15;                       // WU = 1<<15
    const float* W = (w == 0) ? Wq : (w == 1) ? Wk : (w == 2) ? Wv : Wo;
    s = W + (size_t)(r & (WU - 1)) * 8;
  }
  float4 f0 = ((const float4*)s)[0];
  float4 f1 = ((const float4*)s)[1];
  bf16x8 o;
  o[0] = (bf16_t)f0.x; o[1] = (bf16_t)f0.y; o[2] = (bf16_t)f0.z; o[3] = (bf16_t)f0.w;
  o[4] = (bf16_t)f1.x; o[5] = (bf16_t)f1.y; o[6] = (bf16_t)f1.z; o[7] = (bf16_t)f1.w;
  ((bf16x8*)dst)[i] = o;
}

// ---------------------------------------------------------------------------
// qkv GEMM: 256x128 tile, BK=64, z in grid. Wave = 64 rows x 128 cols:
// acc[4][8] (128 AGPR), 64 MFMA per wave per k-iter (2x R7 barrier density).
// XOR chunk swizzle on LDS staging (slot ^ (row&7)) -> conflict-free frags.
// Writes bf16 per-head planes qkv[z][b][h][t][d].
// ---------------------------------------------------------------------------
__global__ __launch_bounds__(256, 2)
void qkv_gemm(const bf16_t* __restrict__ xb, const bf16_t* __restrict__ Wb,
              const float* __restrict__ bq, const float* __restrict__ bk,
              const float* __restrict__ bv, bf16_t* __restrict__ qkv) {
  __shared__ __align__(16) bf16_t lsA[256 * 64];   // 32 KB
  __shared__ __align__(16) bf16_t lsB[128 * 64];   // 16 KB

  const int z    = blockIdx.z;
  const int m0   = blockIdx.y * 256;
  const int n0   = blockIdx.x * 128;
  const bf16_t* W = Wb + (size_t)z * C_ * C_;

  const int tid  = threadIdx.x;
  const int lane = tid & 63;
  const int wave = tid >> 6;
  const int wm   = wave * 64;            // wave's 64-row strip

  f32x4 acc[4][8] = {};

  for (int k0 = 0; k0 < C_; k0 += 64) {
    __syncthreads();   // previous iteration's LDS reads complete
#pragma unroll
    for (int s = 0; s < 8; ++s) {        // A: 2048 units (256 rows x 8 chunks)
      int u    = s * 256 + tid;
      int row  = u >> 3;
      int c    = (u & 7) ^ (row & 7);
      const bf16_t* ga = xb + ((size_t)(m0 + row) * C_ + k0 + c * 8);
      __builtin_amdgcn_global_load_lds(
          (const __attribute__((address_space(1))) unsigned int*)ga,
          (__attribute__((address_space(3))) unsigned int*)&lsA[u * 8], 16, 0, 0);
    }
#pragma unroll
    for (int s = 0; s < 4; ++s) {        // B: 1024 units (128 rows x 8 chunks)
      int u    = s * 256 + tid;
      int row  = u >> 3;
      int c    = (u & 7) ^ (row & 7);
      const bf16_t* gb = W + ((size_t)(n0 + row) * C_ + k0 + c * 8);
      __builtin_amdgcn_global_load_lds(
          (const __attribute__((address_space(1))) unsigned int*)gb,
          (__attribute__((address_space(3))) unsigned int*)&lsB[u * 8], 16, 0, 0);
    }
    __syncthreads();   // vmcnt drained before barrier -> staging visible

    const int rr = lane & 15;
    const int q  = lane >> 4;
#pragma unroll
    for (int kh = 0; kh < 2; ++kh) {
      const int cg = kh * 4 + q;
      const int sl = (cg ^ (rr & 7)) << 3;
      bf16x8 af[4], bfr[8];
#pragma unroll
      for (int i = 0; i < 4; ++i)
        af[i] = *(const bf16x8*)&lsA[(wm + i * 16 + rr) * 64 + sl];
#pragma unroll
      for (int j = 0; j < 8; ++j)
        bfr[j] = *(const bf16x8*)&lsB[(j * 16 + rr) * 64 + sl];
#pragma unroll
      for (int i = 0; i < 4; ++i)
#pragma unroll
        for (int j = 0; j < 8; ++j)
          acc[i][j] = __builtin_amdgcn_mfma_f32_16x16x32_bf16(
              af[i], bfr[j], acc[i][j], 0, 0, 0);
    }
  }

  // Epilogue: C/D layout col = lane&15, row = (lane>>4)*4 + reg  [m89]
  const int cn = lane & 15;
  const int rb = (lane >> 4) << 2;
  const float* bias = (z == 0) ? bq : (z == 1) ? bk : bv;
  float bvals[8];
#pragma unroll
  for (int j = 0; j < 8; ++j) bvals[j] = bias[n0 + j * 16 + cn];

  bf16_t* plz = qkv + (size_t)z * PLANE;
#pragma unroll
  for (int i = 0; i < 4; ++i) {
#pragma unroll
    for (int r = 0; r < 4; ++r) {
      int m  = m0 + wm + i * 16 + rb + r;
      int bb = m >> 12, t = m & (T_ - 1);
#pragma unroll
      for (int j = 0; j < 8; ++j) {
        int col = n0 + j * 16 + cn;
        int h = col >> 6, d = col & 63;
        plz[((size_t)(bb * H_ + h) * T_ + t) * D_ + d] =
            (bf16_t)(acc[i][j][r] + bvals[j]);
      }
    }
  }
}

// ---------------------------------------------------------------------------
// Output GEMM (R7 structure): 128x128, BK=64, A = y per-head planes, swizzle.
// ---------------------------------------------------------------------------
__global__ __launch_bounds__(256, 2)
void out_gemm(const bf16_t* __restrict__ y, const bf16_t* __restrict__ Wob,
              const float* __restrict__ bo, float* __restrict__ out) {
  __shared__ __align__(16) bf16_t lsA[128 * 64];
  __shared__ __align__(16) bf16_t lsB[128 * 64];

  const int tid  = threadIdx.x;
  const int lane = tid & 63;
  const int wave = tid >> 6;
  const int wm   = (wave >> 1) * 64;
  const int wn   = (wave & 1) * 64;
  const int m0   = blockIdx.y * 128;
  const int n0   = blockIdx.x * 128;

  f32x4 acc[4][4] = {};

  for (int k0 = 0; k0 < C_; k0 += 64) {
    __syncthreads();
#pragma unroll
    for (int s = 0; s < 4; ++s) {
      int u    = s * 256 + tid;
      int row  = u >> 3;
      int c    = (u & 7) ^ (row & 7);
      int m = m0 + row;
      int b = m >> 12, t = m & (T_ - 1);
      int h = k0 >> 6;
      const bf16_t* ga = y + (((size_t)(b * H_ + h) * T_ + t) * D_ + c * 8);
      const bf16_t* gb = Wob + ((size_t)(n0 + row) * C_ + k0 + c * 8);
      __builtin_amdgcn_global_load_lds(
          (const __attribute__((address_space(1))) unsigned int*)ga,
          (__attribute__((address_space(3))) unsigned int*)&lsA[u * 8], 16, 0, 0);
      __builtin_amdgcn_global_load_lds(
          (const __attribute__((address_space(1))) unsigned int*)gb,
          (__attribute__((address_space(3))) unsigned int*)&lsB[u * 8], 16, 0, 0);
    }
    __syncthreads();

    const int rr = lane & 15;
    const int q  = lane >> 4;
#pragma unroll
    for (int kh = 0; kh < 2; ++kh) {
      const int cg = kh * 4 + q;
      const int sl = (cg ^ (rr & 7)) << 3;
      bf16x8 af[4], bfr[4];
#pragma unroll
      for (int i = 0; i < 4; ++i) {
        af[i]  = *(const bf16x8*)&lsA[(wm + i * 16 + rr) * 64 + sl];
        bfr[i] = *(const bf16x8*)&lsB[(wn + i * 16 + rr) * 64 + sl];
      }
#pragma unroll
      for (int i = 0; i < 4; ++i)
#pragma unroll
        for (int j = 0; j < 4; ++j)
          acc[i][j] = __builtin_amdgcn_mfma_f32_16x16x32_bf16(
              af[i], bfr[j], acc[i][j], 0, 0, 0);
    }
  }

  const int cn = lane & 15;
  const int rb = (lane >> 4) << 2;
  float bvals[4];
#pragma unroll
  for (int j = 0; j < 4; ++j) bvals[j] = bo[n0 + wn + j * 16 + cn];
#pragma unroll
  for (int i = 0; i < 4; ++i) {
#pragma unroll
    for (int r = 0; r < 4; ++r) {
      int gm = m0 + wm + i * 16 + rb + r;
      float* orow = out + (size_t)gm * C_ + (n0 + wn);
#pragma unroll
      for (int j = 0; j < 4; ++j)
        orow[j * 16 + cn] = acc[i][j][r] + bvals[j];
    }
  }
}

// ---------------------------------------------------------------------------
// Neighborhood attention, LDS-tiled: block = (b, h, 128-t strip). k,v rows
// [t0-4, t0+132) staged in LDS (34.8 KB -> 4 blocks/CU); k,v HBM-fetched
// exactly once (+6% halo). 8 threads per t (d-octet each), width-8 shfl
// score reduction, 4 passes of 32 t's.
// ---------------------------------------------------------------------------
#define AT_T 128
#define AT_R (AT_T + 8)
__global__ __launch_bounds__(256)
void attn_kernel(const bf16_t* __restrict__ qkv, bf16_t* __restrict__ y) {
  __shared__ __align__(16) bf16_t ks[AT_R * D_];
  __shared__ __align__(16) bf16_t vs[AT_R * D_];

  const int tid = threadIdx.x;
  const int t0  = blockIdx.x * AT_T;
  const int h   = blockIdx.y;
  const int b   = blockIdx.z;

  const size_t pl = (size_t)(b * H_ + h) * T_ * D_;
  const bf16_t* kg = qkv + (size_t)PLANE + pl;
  const bf16_t* vg = qkv + (size_t)2 * PLANE + pl;

  // Stage k,v: AT_R rows x 8 chunks of 16 B each.
  for (int c = tid; c < AT_R * 8; c += 256) {
    int r = c >> 3, off = (c & 7) * 8;
    int tg = t0 - PAD_ + r;
    tg = tg < 0 ? 0 : (tg >= T_ ? T_ - 1 : tg);
    *((bf16x8*)ks + c) = *(const bf16x8*)(kg + (size_t)tg * D_ + off);
    *((bf16x8*)vs + c) = *(const bf16x8*)(vg + (size_t)tg * D_ + off);
  }
  __syncthreads();

  const int sub = tid & 7;
  const int tl  = tid >> 3;
  const int c8  = sub * 8;

#pragma unroll
  for (int p = 0; p < AT_T / 32; ++p) {
    const int tloc = p * 32 + tl;
    const int t    = t0 + tloc;

    bf16x8 q8 = *(const bf16x8*)(qkv + pl + (size_t)t * D_ + c8);
    float qf[8];
#pragma unroll
    for (int e = 0; e < 8; ++e) qf[e] = (float)q8[e];

    float s[KS_];
#pragma unroll
    for (int j = 0; j < KS_; ++j) {
      // LDS row for neighbor j of tloc is tloc + j (halo offset built in).
      bf16x8 k8 = *(const bf16x8*)&ks[(tloc + j) * D_ + c8];
      float d0 = 0.f;
#pragma unroll
      for (int e = 0; e < 8; ++e) d0 += qf[e] * (float)k8[e];
      s[j] = d0;
    }

#pragma unroll
    for (int m = 1; m < 8; m <<= 1)
#pragma unroll
      for (int j = 0; j < KS_; ++j) s[j] += __shfl_xor(s[j], m, 8);

    float mx = s[0];
#pragma unroll
    for (int j = 1; j < KS_; ++j) mx = fmaxf(mx, s[j]);
    float w[KS_], sum = 0.f;
#pragma unroll
    for (int j = 0; j < KS_; ++j) {
      w[j] = __expf((s[j] - mx) * 0.125f);   // scale = 1/sqrt(64)
      sum += w[j];
    }
    const float inv = 1.f / sum;
#pragma unroll
    for (int j = 0; j < KS_; ++j) w[j] *= inv;

    float o[8] = {0.f, 0.f, 0.f, 0.f, 0.f, 0.f, 0.f, 0.f};
#pragma unroll
    for (int j = 0; j < KS_; ++j) {
      bf16x8 v8 = *(const bf16x8*)&vs[(tloc + j) * D_ + c8];
#pragma unroll
      for (int e = 0; e < 8; ++e) o[e] += w[j] * (float)v8[e];
    }
    bf16x8 o8;
#pragma unroll
    for (int e = 0; e < 8; ++e) o8[e] = (bf16_t)o[e];
    *(bf16x8*)(y + pl + (size_t)t * D_ + c8) = o8;
  }
}

// ---------------------------------------------------------------------------
extern "C" void kernel_launch(void* const* d_in, const int* in_sizes, int n_in,
                              void* d_out, int out_size, void* d_ws, size_t ws_size,
                              hipStream_t stream) {
  const float* x  = (const float*)d_in[0];
  const float* Wq = (const float*)d_in[1];
  const float* bq = (const float*)d_in[2];
  const float* Wk = (const float*)d_in[3];
  const float* bk = (const float*)d_in[4];
  const float* Wv = (const float*)d_in[5];
  const float* bv = (const float*)d_in[6];
  const float* Wo = (const float*)d_in[7];
  const float* bo = (const float*)d_in[8];
  float* out = (float*)d_out;

  // Workspace: xb 16MB | Wb 2MB | qkv 48MB | y 16MB  = 82 MB
  bf16_t* xb  = (bf16_t*)d_ws;
  bf16_t* Wb  = xb + (size_t)MTOT * C_;
  bf16_t* qkv = Wb + (size_t)4 * C_ * C_;
  bf16_t* y   = qkv + (size_t)3 * PLANE;

  conv_all<<<(XU + 4 * WU) / 256, 256, 0, stream>>>(x, Wq, Wk, Wv, Wo, xb);
  qkv_gemm<<<dim3(C_ / 128, MTOT / 256, 3), 256, 0, stream>>>(
      xb, Wb, bq, bk, bv, qkv);
  attn_kernel<<<dim3(T_ / AT_T, H_, B_), 256, 0, stream>>>(qkv, y);
  out_gemm<<<dim3(C_ / 128, MTOT / 128, 1), 256, 0, stream>>>(
      y, Wb + (size_t)3 * C_ * C_, bo, out);
}